// Round 3
// baseline (679.625 us; speedup 1.0000x reference)
//
#include <hip/hip_runtime.h>
#include <hip/hip_bf16.h>
#include <cstdint>
#include <cstddef>

typedef __bf16 bf16_t;
typedef bf16_t bf16x8 __attribute__((ext_vector_type(8)));
typedef float  f32x4  __attribute__((ext_vector_type(4)));

// ---------------------------------------------------------------------------
// async global->LDS, 16B per lane (global_load_lds_dwordx4)
// ---------------------------------------------------------------------------
__device__ __forceinline__ void gl_lds16(const void* g, void* l) {
  __builtin_amdgcn_global_load_lds(
      (const __attribute__((address_space(1))) void*)g,
      (__attribute__((address_space(3))) void*)l, 16, 0, 0);
}

#define BAR()  __builtin_amdgcn_s_barrier()
#define LGK0() asm volatile("s_waitcnt lgkmcnt(0)" ::: "memory")

// ---------------------------------------------------------------------------
// prep kernel: fused pack_x0 + 6 weight transposes (fp32 -> bf16, K x N -> Npad x Kpad)
// grid 27264 x 256
// ---------------------------------------------------------------------------
__device__ __forceinline__ void transpose_tile(
    const float* __restrict__ W, bf16_t* __restrict__ Wt,
    int K, int N, int Kpad, int Npad, int bx, int by, int t)
{
  __shared__ float tile[32][33];
  const int tx = t & 31, ty = t >> 5;
  const int k0 = bx * 32, n0 = by * 32;
#pragma unroll
  for (int i = 0; i < 4; ++i) {
    int k = k0 + ty + i * 8, n = n0 + tx;
    tile[ty + i * 8][tx] = (k < K && n < N) ? W[(size_t)k * N + n] : 0.f;
  }
  __syncthreads();
#pragma unroll
  for (int i = 0; i < 4; ++i) {
    int n = n0 + ty + i * 8, k = k0 + tx;
    if (n < Npad && k < Kpad)
      Wt[(size_t)n * Kpad + k] = (bf16_t)tile[tx][ty + i * 8];
  }
}

__global__ __launch_bounds__(256) void prep_kernel(
    const float* __restrict__ y, bf16_t* __restrict__ X0,
    const float* __restrict__ eW1, bf16_t* __restrict__ W1t,
    const float* __restrict__ eW2, bf16_t* __restrict__ W2t,
    const float* __restrict__ eW3, bf16_t* __restrict__ W3t,
    const float* __restrict__ dW1, bf16_t* __restrict__ V1t,
    const float* __restrict__ dW2, bf16_t* __restrict__ V2t,
    const float* __restrict__ dW3, bf16_t* __restrict__ V3t)
{
  const int b = blockIdx.x;
  const int t = threadIdx.x;
  if (b < 16000) {
    // pack_x0: y (fp32 [12800][2520]) -> X0 (bf16 [12800][2560])
    const int idx = b * 256 + t;
    const int r = idx / 320, c = (idx % 320) * 8;
    bf16x8 v;
    if (c < 2520) {
      const float4 f0 = *(const float4*)(y + (size_t)r * 2520 + c);
      const float4 f1 = *(const float4*)(y + (size_t)r * 2520 + c + 4);
      v[0] = (bf16_t)f0.x; v[1] = (bf16_t)f0.y; v[2] = (bf16_t)f0.z; v[3] = (bf16_t)f0.w;
      v[4] = (bf16_t)f1.x; v[5] = (bf16_t)f1.y; v[6] = (bf16_t)f1.z; v[7] = (bf16_t)f1.w;
    } else {
#pragma unroll
      for (int j = 0; j < 8; ++j) v[j] = (bf16_t)0.f;
    }
    *(bf16x8*)(X0 + (size_t)r * 2560 + c) = v;
    return;
  }
  int lb = b - 16000;
  if (lb < 2560)      { transpose_tile(eW1, W1t, 2520, 1024, 2560, 1024, lb % 80, lb / 80, t); return; }
  lb -= 2560;
  if (lb < 1024)      { transpose_tile(eW2, W2t, 1024, 1024, 1024, 1024, lb % 32, lb / 32, t); return; }
  lb -= 1024;
  if (lb < 2048)      { transpose_tile(eW3, W3t, 1024, 2048, 1024, 2048, lb % 32, lb / 32, t); return; }
  lb -= 2048;
  if (lb < 2048)      { transpose_tile(dW1, V1t, 2048, 1024, 2048, 1024, lb % 64, lb / 64, t); return; }
  lb -= 2048;
  if (lb < 1024)      { transpose_tile(dW2, V2t, 1024, 1024, 1024, 1024, lb % 32, lb / 32, t); return; }
  lb -= 1024;
  transpose_tile(dW3, V3t, 1024, 2520, 1024, 2560, lb % 32, lb / 32, t);
}

// ---------------------------------------------------------------------------
// swizzled LDS fragment read (st_16x32: byte ^= ((byte>>9)&1)<<5)
// ---------------------------------------------------------------------------
__device__ __forceinline__ bf16x8 ldsfrag(const bf16_t* half_, int r, int kc, int kg) {
  int lin = (r << 7) + (kc << 6) + (kg << 4);   // bytes
  lin ^= ((lin >> 9) & 1) << 5;
  return *(const bf16x8*)((const char*)half_ + lin);
}

// ---------------------------------------------------------------------------
// 256x256x64 8-wave GEMM, 4 phases/K-tile, rolling counted-vmcnt pipeline.
// Per phase: ds_read subtile | stage ONE half-tile of kt+1 | bar | lgk0 | 16 MFMA | bar.
// Boundary: vmcnt(4) at P4 (A-halves), vmcnt(0)+bar inside next P1 before B-reads.
// ---------------------------------------------------------------------------
template<int ELU>
__global__ __launch_bounds__(512, 2) void gemm256(
    const bf16_t* __restrict__ A, const bf16_t* __restrict__ Bt,
    const float* __restrict__ bias,
    bf16_t* __restrict__ Cb, float* __restrict__ Cf,
    int M, int N, int K, int Nlog)
{
  __shared__ __align__(16) bf16_t lds[65536];

  const int t  = threadIdx.x;
  const int w  = t >> 6, l = t & 63;
  const int fr = l & 15, kg = l >> 4;
  const int wm = (w >> 2) * 128, wn = (w & 3) * 64;   // 2M x 4N waves
  const int bro = (wn & 64);

  // bijective XCD-aware remap
  const int gx = gridDim.x;
  const int nwg = gx * (int)gridDim.y;
  int lin = blockIdx.y * gx + blockIdx.x;
  int q8 = nwg >> 3, r8 = nwg & 7, xcd = lin & 7, idx = lin >> 3;
  int swz = (xcd < r8 ? xcd * (q8 + 1) : r8 * (q8 + 1) + (xcd - r8) * q8) + idx;
  const int tn = (swz % gx) * 256;
  const int tm = (swz / gx) * 256;

  // staging: one stage() call = one 128x64 half-tile (2 x 16B DMA per thread).
  const int srow = w * 8 + (l >> 3);                        // 0..63
  const int sce  = ((l & 7) * 8) ^ (((l >> 5) & 1) << 4);   // pre-swizzled src col
  const int sdst = w * 512 + l * 8;                         // linear LDS dest

  const int NT = K >> 6;

  f32x4 acc[8][4];
#pragma unroll
  for (int i = 0; i < 8; ++i)
#pragma unroll
    for (int j = 0; j < 4; ++j) acc[i][j] = (f32x4){0.f, 0.f, 0.f, 0.f};

  auto stage = [&](const bf16_t* gbase, bf16_t* lhalf) {
    gl_lds16(gbase + (size_t)srow * K + sce,        lhalf + sdst);
    gl_lds16(gbase + (size_t)(srow + 64) * K + sce, lhalf + 4096 + sdst);
  };

  // prologue: full tile 0 into slot 0
  stage(A  + (size_t)tm * K,          lds);
  stage(A  + (size_t)(tm + 128) * K,  lds + 8192);
  stage(Bt + (size_t)tn * K,          lds + 16384);
  stage(Bt + (size_t)(tn + 128) * K,  lds + 16384 + 8192);
  asm volatile("s_waitcnt vmcnt(0)" ::: "memory");
  BAR();

  for (int kt = 0; kt < NT; ++kt) {
    const int s = kt & 1;
    const bf16_t* aH = lds + s * 32768 + (wm >> 7) * 8192;
    const bf16_t* bH = lds + s * 32768 + 16384 + (wn >> 7) * 8192;
    bf16_t* aNx = lds + (s ^ 1) * 32768;
    bf16_t* bNx = aNx + 16384;
    const bool pf = (kt + 1 < NT);
    const size_t kn = (size_t)(kt + 1) << 6;

    bf16x8 af[4][2], bf_[2][2];

    // ---- P1: A-reads, drain B of this tile, then B-reads; stage A-half0 ----
#pragma unroll
    for (int mi = 0; mi < 4; ++mi)
#pragma unroll
      for (int kc = 0; kc < 2; ++kc)
        af[mi][kc] = ldsfrag(aH, mi * 16 + fr, kc, kg);
    asm volatile("s_waitcnt vmcnt(0)" ::: "memory");   // own B0,B1 drained
    BAR();                                             // publish all waves' B
#pragma unroll
    for (int nj = 0; nj < 2; ++nj)
#pragma unroll
      for (int kc = 0; kc < 2; ++kc)
        bf_[nj][kc] = ldsfrag(bH, bro + nj * 16 + fr, kc, kg);
    if (pf) stage(A + (size_t)tm * K + kn, aNx);       // A-half0 of kt+1
    BAR(); LGK0();
    __builtin_amdgcn_s_setprio(1);
#pragma unroll
    for (int mi = 0; mi < 4; ++mi)
#pragma unroll
      for (int nj = 0; nj < 2; ++nj)
#pragma unroll
        for (int kc = 0; kc < 2; ++kc)
          acc[mi][nj] = __builtin_amdgcn_mfma_f32_16x16x32_bf16(af[mi][kc], bf_[nj][kc], acc[mi][nj], 0, 0, 0);
    __builtin_amdgcn_s_setprio(0);
    BAR();

    // ---- P2: B[2:4]; stage A-half1 ----
#pragma unroll
    for (int nj = 0; nj < 2; ++nj)
#pragma unroll
      for (int kc = 0; kc < 2; ++kc)
        bf_[nj][kc] = ldsfrag(bH, bro + (nj + 2) * 16 + fr, kc, kg);
    if (pf) stage(A + (size_t)(tm + 128) * K + kn, aNx + 8192);
    BAR(); LGK0();
    __builtin_amdgcn_s_setprio(1);
#pragma unroll
    for (int mi = 0; mi < 4; ++mi)
#pragma unroll
      for (int nj = 0; nj < 2; ++nj)
#pragma unroll
        for (int kc = 0; kc < 2; ++kc)
          acc[mi][nj + 2] = __builtin_amdgcn_mfma_f32_16x16x32_bf16(af[mi][kc], bf_[nj][kc], acc[mi][nj + 2], 0, 0, 0);
    __builtin_amdgcn_s_setprio(0);
    BAR();

    // ---- P3: A[4:8]; stage B-half0 ----
#pragma unroll
    for (int mi = 0; mi < 4; ++mi)
#pragma unroll
      for (int kc = 0; kc < 2; ++kc)
        af[mi][kc] = ldsfrag(aH, (mi + 4) * 16 + fr, kc, kg);
    if (pf) stage(Bt + (size_t)tn * K + kn, bNx);
    BAR(); LGK0();
    __builtin_amdgcn_s_setprio(1);
#pragma unroll
    for (int mi = 0; mi < 4; ++mi)
#pragma unroll
      for (int nj = 0; nj < 2; ++nj)
#pragma unroll
        for (int kc = 0; kc < 2; ++kc)
          acc[mi + 4][nj + 2] = __builtin_amdgcn_mfma_f32_16x16x32_bf16(af[mi][kc], bf_[nj][kc], acc[mi + 4][nj + 2], 0, 0, 0);
    __builtin_amdgcn_s_setprio(0);
    BAR();

    // ---- P4: B[0:2] again; stage B-half1; vmcnt(4) covers A-halves ----
#pragma unroll
    for (int nj = 0; nj < 2; ++nj)
#pragma unroll
      for (int kc = 0; kc < 2; ++kc)
        bf_[nj][kc] = ldsfrag(bH, bro + nj * 16 + fr, kc, kg);
    if (pf) stage(Bt + (size_t)(tn + 128) * K + kn, bNx + 8192);
    asm volatile("s_waitcnt vmcnt(4)" ::: "memory");   // A0,A1 of kt+1 landed
    BAR(); LGK0();
    __builtin_amdgcn_s_setprio(1);
#pragma unroll
    for (int mi = 0; mi < 4; ++mi)
#pragma unroll
      for (int nj = 0; nj < 2; ++nj)
#pragma unroll
        for (int kc = 0; kc < 2; ++kc)
          acc[mi + 4][nj] = __builtin_amdgcn_mfma_f32_16x16x32_bf16(af[mi][kc], bf_[nj][kc], acc[mi + 4][nj], 0, 0, 0);
    __builtin_amdgcn_s_setprio(0);
    BAR();
  }

  // epilogue: C/D layout col = lane&15, row = (lane>>4)*4 + reg
#pragma unroll
  for (int mi = 0; mi < 8; ++mi) {
    const int row0 = tm + wm + mi * 16 + kg * 4;
#pragma unroll
    for (int nj = 0; nj < 4; ++nj) {
      const int col = tn + wn + nj * 16 + fr;
      const float bv = (col < Nlog) ? bias[col] : 0.f;
#pragma unroll
      for (int r = 0; r < 4; ++r) {
        float v = acc[mi][nj][r] + bv;
        if (ELU) v = (v > 0.f) ? v : expm1f(v);
        const int row = row0 + r;
        if (Cb) Cb[(size_t)row * N + col] = (bf16_t)v;
        if (Cf && col < Nlog) Cf[(size_t)row * Nlog + col] = v;
      }
    }
  }
}

// ---------------------------------------------------------------------------
// MFMA VQ: d = 0.5*||e||^2 - <z,e> via 16x16x32 bf16 MFMA (K padded with 0s).
// Tile = 16 groups of one ze row; 8 MFMA (128 codes); butterfly argmin.
// grid 1600 x 256 (4 waves x 16 tiles each).
// ---------------------------------------------------------------------------
__global__ __launch_bounds__(256) void vq_mfma(
    const float* __restrict__ ze, const float* __restrict__ emb,
    float* __restrict__ zq, bf16_t* __restrict__ zqb)
{
  __shared__ float  se[2048];
  __shared__ bf16_t seb[2048];
  const int t = threadIdx.x;
  for (int i = t; i < 2048; i += 256) { float v = emb[i]; se[i] = v; seb[i] = (bf16_t)v; }
  __syncthreads();

  const int l = t & 63, w = t >> 6;
  const int col = l & 15;           // code-within-block / token-col
  const int ks8 = (l >> 4) * 8;     // k-start for this lane (0,8,16,24)
  const bool kact = (ks8 < 16);     // real K = 16; lanes 2,3 hold zeros

  // B fragments (8 code blocks) + h = 0.5*||e||^2 per lane's code
  bf16x8 bfrag[8];
  float  hv[8];
#pragma unroll
  for (int cb = 0; cb < 8; ++cb) {
    float s = 0.f;
    bf16x8 bf;
#pragma unroll
    for (int j = 0; j < 8; ++j) bf[j] = (bf16_t)0.f;
    if (kact) {
      const float* ep = se + (cb * 16 + col) * 16 + ks8;
      float4 e0 = *(const float4*)ep;
      float4 e1 = *(const float4*)(ep + 4);
      bf[0] = (bf16_t)e0.x; bf[1] = (bf16_t)e0.y; bf[2] = (bf16_t)e0.z; bf[3] = (bf16_t)e0.w;
      bf[4] = (bf16_t)e1.x; bf[5] = (bf16_t)e1.y; bf[6] = (bf16_t)e1.z; bf[7] = (bf16_t)e1.w;
      s = e0.x*e0.x + e0.y*e0.y + e0.z*e0.z + e0.w*e0.w
        + e1.x*e1.x + e1.y*e1.y + e1.z*e1.z + e1.w*e1.w;
    }
    s += __shfl_xor(s, 16);
    s += __shfl_xor(s, 32);
    bfrag[cb] = bf;
    hv[cb] = 0.5f * s;
  }

  const int base_tile = blockIdx.x * 64 + w * 16;
  for (int it = 0; it < 16; ++it) {
    const int tile = base_tile + it;
    const int row = tile >> 3, g0 = (tile & 7) * 16;

    bf16x8 afrag;
#pragma unroll
    for (int j = 0; j < 8; ++j) afrag[j] = (bf16_t)0.f;
    if (kact) {
      const float* ap = ze + (size_t)row * 2048 + (g0 + col) * 16 + ks8;
      float4 a0 = *(const float4*)ap;
      float4 a1 = *(const float4*)(ap + 4);
      afrag[0] = (bf16_t)(-a0.x); afrag[1] = (bf16_t)(-a0.y);
      afrag[2] = (bf16_t)(-a0.z); afrag[3] = (bf16_t)(-a0.w);
      afrag[4] = (bf16_t)(-a1.x); afrag[5] = (bf16_t)(-a1.y);
      afrag[6] = (bf16_t)(-a1.z); afrag[7] = (bf16_t)(-a1.w);
    }

    f32x4 dd[8];
#pragma unroll
    for (int cb = 0; cb < 8; ++cb) {
      f32x4 c = (f32x4){hv[cb], hv[cb], hv[cb], hv[cb]};
      dd[cb] = __builtin_amdgcn_mfma_f32_16x16x32_bf16(afrag, bfrag[cb], c, 0, 0, 0);
    }

    // argmin per row (token): local over 8 code-blocks, then 16-lane butterfly
#pragma unroll
    for (int r = 0; r < 4; ++r) {
      float bd = dd[0][r]; int bi = col;
#pragma unroll
      for (int cb = 1; cb < 8; ++cb) {
        float v = dd[cb][r];
        int   ci = cb * 16 + col;
        if (v < bd) { bd = v; bi = ci; }
      }
#pragma unroll
      for (int m = 1; m < 16; m <<= 1) {
        float od = __shfl_xor(bd, m);
        int   oi = __shfl_xor(bi, m);
        if (od < bd || (od == bd && oi < bi)) { bd = od; bi = oi; }
      }
      // lane col==r writes token (l>>4)*4 + r
      if (col == r) {
        const int tok = (l >> 4) * 4 + r;                 // 0..15 within tile
        const size_t go = ((size_t)row * 128 + g0 + tok) * 16;
        const float*  e  = se  + bi * 16;
        const bf16_t* eb = seb + bi * 16;
#pragma unroll
        for (int v = 0; v < 4; ++v)
          *(float4*)(zq + go + v * 4) = ((const float4*)e)[v];
        *(bf16x8*)(zqb + go)     = ((const bf16x8*)eb)[0];
        *(bf16x8*)(zqb + go + 8) = ((const bf16x8*)eb)[1];
      }
    }
  }
}

// ---------------------------------------------------------------------------
extern "C" void kernel_launch(void* const* d_in, const int* in_sizes, int n_in,
                              void* d_out, int out_size, void* d_ws, size_t ws_size,
                              hipStream_t stream)
{
  const float* y   = (const float*)d_in[0];
  const float* emb = (const float*)d_in[1];
  const float* eW1 = (const float*)d_in[2];
  const float* eb1 = (const float*)d_in[3];
  const float* eW2 = (const float*)d_in[4];
  const float* eb2 = (const float*)d_in[5];
  const float* eW3 = (const float*)d_in[6];
  const float* eb3 = (const float*)d_in[7];
  const float* dW1 = (const float*)d_in[8];
  const float* db1 = (const float*)d_in[9];
  const float* dW2 = (const float*)d_in[10];
  const float* db2 = (const float*)d_in[11];
  const float* dW3 = (const float*)d_in[12];
  const float* db3 = (const float*)d_in[13];

  float* out = (float*)d_out;               // [12800][2520]
  float* ze  = out + 32256000;              // [12800][2048]
  float* zq  = ze + 26214400;               // [12800][2048]

  uint8_t* ws = (uint8_t*)d_ws;
  size_t off = 0;
  auto alloc = [&](size_t bytes) -> void* {
    void* p = ws + off; off += (bytes + 255) & ~(size_t)255; return p;
  };
  bf16_t* X0  = (bf16_t*)alloc(12800ULL * 2560 * 2);
  bf16_t* W1t = (bf16_t*)alloc(1024ULL * 2560 * 2);
  bf16_t* W2t = (bf16_t*)alloc(1024ULL * 1024 * 2);
  bf16_t* W3t = (bf16_t*)alloc(2048ULL * 1024 * 2);
  bf16_t* V1t = (bf16_t*)alloc(1024ULL * 2048 * 2);
  bf16_t* V2t = (bf16_t*)alloc(1024ULL * 1024 * 2);
  bf16_t* V3t = (bf16_t*)alloc(2560ULL * 1024 * 2);
  bf16_t* H1  = (bf16_t*)alloc(12800ULL * 1024 * 2);
  bf16_t* H2  = (bf16_t*)alloc(12800ULL * 1024 * 2);
  bf16_t* ZQb = (bf16_t*)alloc(12800ULL * 2048 * 2);

  prep_kernel<<<27264, 256, 0, stream>>>(y, X0, eW1, W1t, eW2, W2t, eW3, W3t,
                                         dW1, V1t, dW2, V2t, dW3, V3t);

  // encoder
  gemm256<1><<<dim3(4, 50), 512, 0, stream>>>(X0, W1t, eb1, H1, nullptr, 12800, 1024, 2560, 1024);
  gemm256<1><<<dim3(4, 50), 512, 0, stream>>>(H1, W2t, eb2, H2, nullptr, 12800, 1024, 1024, 1024);
  gemm256<0><<<dim3(8, 50), 512, 0, stream>>>(H2, W3t, eb3, nullptr, ze, 12800, 2048, 1024, 2048);
  // vector quantize
  vq_mfma<<<1600, 256, 0, stream>>>(ze, emb, zq, ZQb);
  // decoder
  gemm256<1><<<dim3(4, 50), 512, 0, stream>>>(ZQb, V1t, db1, H1, nullptr, 12800, 1024, 2048, 1024);
  gemm256<1><<<dim3(4, 50), 512, 0, stream>>>(H1, V2t, db2, H2, nullptr, 12800, 1024, 1024, 1024);
  gemm256<0><<<dim3(10, 50), 512, 0, stream>>>(H2, V3t, db3, nullptr, out, 12800, 2560, 1024, 2520);
}

// Round 4
// 662.460 us; speedup vs baseline: 1.0259x; 1.0259x over previous
//
#include <hip/hip_runtime.h>
#include <hip/hip_bf16.h>
#include <cstdint>
#include <cstddef>

typedef __bf16 bf16_t;
typedef bf16_t bf16x8 __attribute__((ext_vector_type(8)));
typedef float  f32x4  __attribute__((ext_vector_type(4)));

// ---------------------------------------------------------------------------
// async global->LDS, 16B per lane (global_load_lds_dwordx4)
// ---------------------------------------------------------------------------
__device__ __forceinline__ void gl_lds16(const void* g, void* l) {
  __builtin_amdgcn_global_load_lds(
      (const __attribute__((address_space(1))) void*)g,
      (__attribute__((address_space(3))) void*)l, 16, 0, 0);
}

#define BAR()  __builtin_amdgcn_s_barrier()
#define LGK0() asm volatile("s_waitcnt lgkmcnt(0)" ::: "memory")

// ---------------------------------------------------------------------------
// prep kernel: fused pack_x0 + 6 weight transposes (fp32 -> bf16, KxN -> Npad x Kpad)
// ---------------------------------------------------------------------------
__device__ __forceinline__ void transpose_tile(
    const float* __restrict__ W, bf16_t* __restrict__ Wt,
    int K, int N, int Kpad, int Npad, int bx, int by, int t)
{
  __shared__ float tile[32][33];
  const int tx = t & 31, ty = t >> 5;
  const int k0 = bx * 32, n0 = by * 32;
#pragma unroll
  for (int i = 0; i < 4; ++i) {
    int k = k0 + ty + i * 8, n = n0 + tx;
    tile[ty + i * 8][tx] = (k < K && n < N) ? W[(size_t)k * N + n] : 0.f;
  }
  __syncthreads();
#pragma unroll
  for (int i = 0; i < 4; ++i) {
    int n = n0 + ty + i * 8, k = k0 + tx;
    if (n < Npad && k < Kpad)
      Wt[(size_t)n * Kpad + k] = (bf16_t)tile[tx][ty + i * 8];
  }
}

__global__ __launch_bounds__(256) void prep_kernel(
    const float* __restrict__ y, bf16_t* __restrict__ X0,
    const float* __restrict__ eW1, bf16_t* __restrict__ W1t,
    const float* __restrict__ eW2, bf16_t* __restrict__ W2t,
    const float* __restrict__ eW3, bf16_t* __restrict__ W3t,
    const float* __restrict__ dW1, bf16_t* __restrict__ V1t,
    const float* __restrict__ dW2, bf16_t* __restrict__ V2t,
    const float* __restrict__ dW3, bf16_t* __restrict__ V3t)
{
  const int b = blockIdx.x;
  const int t = threadIdx.x;
  if (b < 16000) {
    const int idx = b * 256 + t;
    const int r = idx / 320, c = (idx % 320) * 8;
    bf16x8 v;
    if (c < 2520) {
      const float4 f0 = *(const float4*)(y + (size_t)r * 2520 + c);
      const float4 f1 = *(const float4*)(y + (size_t)r * 2520 + c + 4);
      v[0] = (bf16_t)f0.x; v[1] = (bf16_t)f0.y; v[2] = (bf16_t)f0.z; v[3] = (bf16_t)f0.w;
      v[4] = (bf16_t)f1.x; v[5] = (bf16_t)f1.y; v[6] = (bf16_t)f1.z; v[7] = (bf16_t)f1.w;
    } else {
#pragma unroll
      for (int j = 0; j < 8; ++j) v[j] = (bf16_t)0.f;
    }
    *(bf16x8*)(X0 + (size_t)r * 2560 + c) = v;
    return;
  }
  int lb = b - 16000;
  if (lb < 2560)      { transpose_tile(eW1, W1t, 2520, 1024, 2560, 1024, lb % 80, lb / 80, t); return; }
  lb -= 2560;
  if (lb < 1024)      { transpose_tile(eW2, W2t, 1024, 1024, 1024, 1024, lb % 32, lb / 32, t); return; }
  lb -= 1024;
  if (lb < 2048)      { transpose_tile(eW3, W3t, 1024, 2048, 1024, 2048, lb % 32, lb / 32, t); return; }
  lb -= 2048;
  if (lb < 2048)      { transpose_tile(dW1, V1t, 2048, 1024, 2048, 1024, lb % 64, lb / 64, t); return; }
  lb -= 2048;
  if (lb < 1024)      { transpose_tile(dW2, V2t, 1024, 1024, 1024, 1024, lb % 32, lb / 32, t); return; }
  lb -= 1024;
  transpose_tile(dW3, V3t, 1024, 2520, 1024, 2560, lb % 32, lb / 32, t);
}

// ---------------------------------------------------------------------------
// 256x256 GEMM, BK=32, 4 LDS slots, depth-3 prefetch, ONE counted vmcnt(8)
// per K-tile (never drains to 0). 8 waves (2M x 4N), wave tile 128x64.
// LDS slot = [A 256x32 | B 256x32] bf16 = 32KB; 4 slots = 128KB.
// BK=32 row stride (64B) makes fragment reads naturally bank-balanced.
// C[M][N] = A[M][K] @ Bt[N][K]^T + bias, optional ELU.
// Requires M%256==0, N%256==0, K%32==0, K/32 >= 4.
// ---------------------------------------------------------------------------
template<int ELU>
__global__ __launch_bounds__(512, 2) void gemm256(
    const bf16_t* __restrict__ A, const bf16_t* __restrict__ Bt,
    const float* __restrict__ bias,
    bf16_t* __restrict__ Cb, float* __restrict__ Cf,
    int M, int N, int K, int Nlog)
{
  __shared__ __align__(16) bf16_t lds[65536];   // 4 x 16384 elems

  const int t  = threadIdx.x;
  const int w  = t >> 6, l = t & 63;
  const int fr = l & 15, kg = l >> 4;
  const int wm = (w >> 2) * 128, wn = (w & 3) * 64;   // 2M x 4N waves

  // bijective XCD-aware remap
  const int gx = gridDim.x;
  const int nwg = gx * (int)gridDim.y;
  int lin = blockIdx.y * gx + blockIdx.x;
  int q8 = nwg >> 3, r8 = nwg & 7, xcd = lin & 7, idx = lin >> 3;
  int swz = (xcd < r8 ? xcd * (q8 + 1) : r8 * (q8 + 1) + (xcd - r8) * q8) + idx;
  const int tn = (swz % gx) * 256;
  const int tm = (swz / gx) * 256;

  // staging: per K-tile, A chunk (256x32) and B chunk (256x32), 2 x 16B/thread each.
  // round r: thread covers row r*128 + (t>>2), col (t&3)*8 elems; dest r*4096 + t*8.
  const int srow = t >> 2;
  const int scol = (t & 3) * 8;
  const int sdst = t * 8;

  const int NT = K >> 5;

  f32x4 acc[8][4];
#pragma unroll
  for (int i = 0; i < 8; ++i)
#pragma unroll
    for (int j = 0; j < 4; ++j) acc[i][j] = (f32x4){0.f, 0.f, 0.f, 0.f};

  auto stageA = [&](int slot, int kn) {
    bf16_t* d = lds + slot * 16384;
    gl_lds16(A + (size_t)(tm + srow) * K + kn + scol,       d + sdst);
    gl_lds16(A + (size_t)(tm + 128 + srow) * K + kn + scol, d + 4096 + sdst);
  };
  auto stageB = [&](int slot, int kn) {
    bf16_t* d = lds + slot * 16384 + 8192;
    gl_lds16(Bt + (size_t)(tn + srow) * K + kn + scol,       d + sdst);
    gl_lds16(Bt + (size_t)(tn + 128 + srow) * K + kn + scol, d + 4096 + sdst);
  };

  // prologue: stage tiles 0,1,2; wait so tile 0 (oldest 4 loads) is resident.
  stageA(0, 0);  stageB(0, 0);
  stageA(1, 32); stageB(1, 32);
  stageA(2, 64); stageB(2, 64);
  asm volatile("s_waitcnt vmcnt(8)" ::: "memory");
  BAR();

  for (int kt = 0; kt < NT; ++kt) {
    const int slot = kt & 3;
    const bf16_t* aH = lds + slot * 16384 + wm * 32;          // wave's 128-row A view
    const bf16_t* bH = lds + slot * 16384 + 8192 + wn * 32;   // wave's 64-row B view
    const bool pf = (kt + 3 < NT);
    const int ps = (kt + 3) & 3;
    const int kn = (kt + 3) << 5;

    bf16x8 af[8], bf_[2];

    // ---- P1: all A-frags + B[0:2]; stage next A ----
#pragma unroll
    for (int mi = 0; mi < 8; ++mi)
      af[mi] = *(const bf16x8*)(aH + (mi * 16 + fr) * 32 + kg * 8);
#pragma unroll
    for (int nj = 0; nj < 2; ++nj)
      bf_[nj] = *(const bf16x8*)(bH + (nj * 16 + fr) * 32 + kg * 8);
    if (pf) stageA(ps, kn);
    BAR(); LGK0();
    __builtin_amdgcn_s_setprio(1);
#pragma unroll
    for (int mi = 0; mi < 8; ++mi)
#pragma unroll
      for (int nj = 0; nj < 2; ++nj)
        acc[mi][nj] = __builtin_amdgcn_mfma_f32_16x16x32_bf16(af[mi], bf_[nj], acc[mi][nj], 0, 0, 0);
    __builtin_amdgcn_s_setprio(0);
    BAR();

    // ---- P2: B[2:4]; stage next B; counted vmcnt before final barrier ----
#pragma unroll
    for (int nj = 0; nj < 2; ++nj)
      bf_[nj] = *(const bf16x8*)(bH + ((nj + 2) * 16 + fr) * 32 + kg * 8);
    if (pf) stageB(ps, kn);
    BAR(); LGK0();
    __builtin_amdgcn_s_setprio(1);
#pragma unroll
    for (int mi = 0; mi < 8; ++mi)
#pragma unroll
      for (int nj = 0; nj < 2; ++nj)
        acc[mi][nj + 2] = __builtin_amdgcn_mfma_f32_16x16x32_bf16(af[mi], bf_[nj], acc[mi][nj + 2], 0, 0, 0);
    __builtin_amdgcn_s_setprio(0);
    // loads issued after tile kt+1's staging = tiles kt+2,kt+3 = 8 -> exact count
    asm volatile("s_waitcnt vmcnt(8)" ::: "memory");
    BAR();
  }

  // epilogue: C/D layout col = lane&15, row = (lane>>4)*4 + reg
#pragma unroll
  for (int mi = 0; mi < 8; ++mi) {
    const int row0 = tm + wm + mi * 16 + kg * 4;
#pragma unroll
    for (int nj = 0; nj < 4; ++nj) {
      const int col = tn + wn + nj * 16 + fr;
      const float bv = (col < Nlog) ? bias[col] : 0.f;
#pragma unroll
      for (int r = 0; r < 4; ++r) {
        float v = acc[mi][nj][r] + bv;
        if (ELU) v = (v > 0.f) ? v : expm1f(v);
        const int row = row0 + r;
        if (Cb) Cb[(size_t)row * N + col] = (bf16_t)v;
        if (Cf && col < Nlog) Cf[(size_t)row * Nlog + col] = v;
      }
    }
  }
}

// ---------------------------------------------------------------------------
// MFMA VQ: d = 0.5*||e||^2 - <z,e> via 16x16x32 bf16 MFMA (K padded with 0s).
// ---------------------------------------------------------------------------
__global__ __launch_bounds__(256) void vq_mfma(
    const float* __restrict__ ze, const float* __restrict__ emb,
    float* __restrict__ zq, bf16_t* __restrict__ zqb)
{
  __shared__ float  se[2048];
  __shared__ bf16_t seb[2048];
  const int t = threadIdx.x;
  for (int i = t; i < 2048; i += 256) { float v = emb[i]; se[i] = v; seb[i] = (bf16_t)v; }
  __syncthreads();

  const int l = t & 63, w = t >> 6;
  const int col = l & 15;
  const int ks8 = (l >> 4) * 8;
  const bool kact = (ks8 < 16);

  bf16x8 bfrag[8];
  float  hv[8];
#pragma unroll
  for (int cb = 0; cb < 8; ++cb) {
    float s = 0.f;
    bf16x8 bf;
#pragma unroll
    for (int j = 0; j < 8; ++j) bf[j] = (bf16_t)0.f;
    if (kact) {
      const float* ep = se + (cb * 16 + col) * 16 + ks8;
      float4 e0 = *(const float4*)ep;
      float4 e1 = *(const float4*)(ep + 4);
      bf[0] = (bf16_t)e0.x; bf[1] = (bf16_t)e0.y; bf[2] = (bf16_t)e0.z; bf[3] = (bf16_t)e0.w;
      bf[4] = (bf16_t)e1.x; bf[5] = (bf16_t)e1.y; bf[6] = (bf16_t)e1.z; bf[7] = (bf16_t)e1.w;
      s = e0.x*e0.x + e0.y*e0.y + e0.z*e0.z + e0.w*e0.w
        + e1.x*e1.x + e1.y*e1.y + e1.z*e1.z + e1.w*e1.w;
    }
    s += __shfl_xor(s, 16);
    s += __shfl_xor(s, 32);
    bfrag[cb] = bf;
    hv[cb] = 0.5f * s;
  }

  const int base_tile = blockIdx.x * 64 + w * 16;
  for (int it = 0; it < 16; ++it) {
    const int tile = base_tile + it;
    const int row = tile >> 3, g0 = (tile & 7) * 16;

    bf16x8 afrag;
#pragma unroll
    for (int j = 0; j < 8; ++j) afrag[j] = (bf16_t)0.f;
    if (kact) {
      const float* ap = ze + (size_t)row * 2048 + (g0 + col) * 16 + ks8;
      float4 a0 = *(const float4*)ap;
      float4 a1 = *(const float4*)(ap + 4);
      afrag[0] = (bf16_t)(-a0.x); afrag[1] = (bf16_t)(-a0.y);
      afrag[2] = (bf16_t)(-a0.z); afrag[3] = (bf16_t)(-a0.w);
      afrag[4] = (bf16_t)(-a1.x); afrag[5] = (bf16_t)(-a1.y);
      afrag[6] = (bf16_t)(-a1.z); afrag[7] = (bf16_t)(-a1.w);
    }

    f32x4 dd[8];
#pragma unroll
    for (int cb = 0; cb < 8; ++cb) {
      f32x4 c = (f32x4){hv[cb], hv[cb], hv[cb], hv[cb]};
      dd[cb] = __builtin_amdgcn_mfma_f32_16x16x32_bf16(afrag, bfrag[cb], c, 0, 0, 0);
    }

#pragma unroll
    for (int r = 0; r < 4; ++r) {
      float bd = dd[0][r]; int bi = col;
#pragma unroll
      for (int cb = 1; cb < 8; ++cb) {
        float v = dd[cb][r];
        int   ci = cb * 16 + col;
        if (v < bd) { bd = v; bi = ci; }
      }
#pragma unroll
      for (int m = 1; m < 16; m <<= 1) {
        float od = __shfl_xor(bd, m);
        int   oi = __shfl_xor(bi, m);
        if (od < bd || (od == bd && oi < bi)) { bd = od; bi = oi; }
      }
      if (col == r) {
        const int tok = (l >> 4) * 4 + r;
        const size_t go = ((size_t)row * 128 + g0 + tok) * 16;
        const float*  e  = se  + bi * 16;
        const bf16_t* eb = seb + bi * 16;
#pragma unroll
        for (int v = 0; v < 4; ++v)
          *(float4*)(zq + go + v * 4) = ((const float4*)e)[v];
        *(bf16x8*)(zqb + go)     = ((const bf16x8*)eb)[0];
        *(bf16x8*)(zqb + go + 8) = ((const bf16x8*)eb)[1];
      }
    }
  }
}

// ---------------------------------------------------------------------------
extern "C" void kernel_launch(void* const* d_in, const int* in_sizes, int n_in,
                              void* d_out, int out_size, void* d_ws, size_t ws_size,
                              hipStream_t stream)
{
  const float* y   = (const float*)d_in[0];
  const float* emb = (const float*)d_in[1];
  const float* eW1 = (const float*)d_in[2];
  const float* eb1 = (const float*)d_in[3];
  const float* eW2 = (const float*)d_in[4];
  const float* eb2 = (const float*)d_in[5];
  const float* eW3 = (const float*)d_in[6];
  const float* eb3 = (const float*)d_in[7];
  const float* dW1 = (const float*)d_in[8];
  const float* db1 = (const float*)d_in[9];
  const float* dW2 = (const float*)d_in[10];
  const float* db2 = (const float*)d_in[11];
  const float* dW3 = (const float*)d_in[12];
  const float* db3 = (const float*)d_in[13];

  float* out = (float*)d_out;               // [12800][2520]
  float* ze  = out + 32256000;              // [12800][2048]
  float* zq  = ze + 26214400;               // [12800][2048]

  uint8_t* ws = (uint8_t*)d_ws;
  size_t off = 0;
  auto alloc = [&](size_t bytes) -> void* {
    void* p = ws + off; off += (bytes + 255) & ~(size_t)255; return p;
  };
  bf16_t* X0  = (bf16_t*)alloc(12800ULL * 2560 * 2);
  bf16_t* W1t = (bf16_t*)alloc(1024ULL * 2560 * 2);
  bf16_t* W2t = (bf16_t*)alloc(1024ULL * 1024 * 2);
  bf16_t* W3t = (bf16_t*)alloc(2048ULL * 1024 * 2);
  bf16_t* V1t = (bf16_t*)alloc(1024ULL * 2048 * 2);
  bf16_t* V2t = (bf16_t*)alloc(1024ULL * 1024 * 2);
  bf16_t* V3t = (bf16_t*)alloc(2560ULL * 1024 * 2);
  bf16_t* H1  = (bf16_t*)alloc(12800ULL * 1024 * 2);
  bf16_t* H2  = (bf16_t*)alloc(12800ULL * 1024 * 2);
  bf16_t* ZQb = (bf16_t*)alloc(12800ULL * 2048 * 2);

  prep_kernel<<<27264, 256, 0, stream>>>(y, X0, eW1, W1t, eW2, W2t, eW3, W3t,
                                         dW1, V1t, dW2, V2t, dW3, V3t);

  // encoder
  gemm256<1><<<dim3(4, 50), 512, 0, stream>>>(X0, W1t, eb1, H1, nullptr, 12800, 1024, 2560, 1024);
  gemm256<1><<<dim3(4, 50), 512, 0, stream>>>(H1, W2t, eb2, H2, nullptr, 12800, 1024, 1024, 1024);
  gemm256<0><<<dim3(8, 50), 512, 0, stream>>>(H2, W3t, eb3, nullptr, ze, 12800, 2048, 1024, 2048);
  // vector quantize
  vq_mfma<<<1600, 256, 0, stream>>>(ze, emb, zq, ZQb);
  // decoder
  gemm256<1><<<dim3(4, 50), 512, 0, stream>>>(ZQb, V1t, db1, H1, nullptr, 12800, 1024, 2048, 1024);
  gemm256<1><<<dim3(4, 50), 512, 0, stream>>>(H1, V2t, db2, H2, nullptr, 12800, 1024, 1024, 1024);
  gemm256<0><<<dim3(10, 50), 512, 0, stream>>>(H2, V3t, db3, nullptr, out, 12800, 2560, 1024, 2520);
}